// Round 10
// baseline (4437.947 us; speedup 1.0000x reference)
//
#include <hip/hip_runtime.h>

#define HH 50
#define NGATE 200      // 4*H gate rows
#define NB 4           // batch elements per block -> grid 512 = 2 blocks/CU
#define TT 512
#define NTH 512
#define NTILES 13      // ceil(200/16)
#define A0S 72         // shorts/row: 64 k-slots (54 used: h|x|1) + 8 pad = 144B
#define A1S 136        // shorts/row: 128 k-slots (101 used: h1|hB|1) + 8 pad = 272B
#define GS 20          // g row stride (floats), rows indexed by gate n
#define NFRAG (NTILES * 12)   // 12 fragment slots per N-tile

typedef __attribute__((ext_vector_type(8))) short short8;
typedef __attribute__((ext_vector_type(4))) float f32x4;

__device__ __forceinline__ unsigned short f2bf(float f) {
    unsigned int u = __float_as_uint(f);
    u += 0x7FFFu + ((u >> 16) & 1u);
    return (unsigned short)(u >> 16);
}
__device__ __forceinline__ float bf2f(unsigned short s) {
    return __uint_as_float(((unsigned int)s) << 16);
}
__device__ __forceinline__ float fast_sigmoid(float v) {
    v = fminf(fmaxf(v, -30.f), 30.f);
    return 1.f / (1.f + __expf(-v));
}
__device__ __forceinline__ float fast_tanh(float v) {
    v = fminf(fmaxf(v, -15.f), 15.f);
    float e = __expf(2.f * v);
    return (e - 1.f) / (e + 1.f);
}
__device__ __forceinline__ float cell_h(float pi, float pf, float pg, float po, float& c) {
    float ii = fast_sigmoid(pi), ff = fast_sigmoid(pf);
    float gg = fast_tanh(pg),    oo = fast_sigmoid(po);
    c = ff * c + ii * gg;
    return oo * fast_tanh(c);
}

// ---------------- prep kernel: build split-bf16 B-fragments in d_ws ----------------
// slot map per N-tile nt:
//   slot 0..3  : layer0 kt{0,1} x {hi,lo}   (K = [Whh0(50)|Wih0(3)|bias1])
//   slot 4..11 : layer1 kt{0..3} x {hi,lo}  (K = [Wih1(50)|Whh1(50)|bias1])
__global__ void prep_frags(
    const float* __restrict__ W_ih0, const float* __restrict__ W_hh0,
    const float* __restrict__ b_ih0, const float* __restrict__ b_hh0,
    const float* __restrict__ W_ih1, const float* __restrict__ W_hh1,
    const float* __restrict__ b_ih1, const float* __restrict__ b_hh1,
    unsigned short* __restrict__ ws)
{
    int idx = blockIdx.x * blockDim.x + threadIdx.x;
    if (idx >= NFRAG * 64) return;
    const int lane = idx & 63;
    const int fid  = idx >> 6;
    const int nt   = fid / 12;
    const int slot = fid - nt * 12;
    const int n    = nt * 16 + (lane & 15);
    const int q4   = lane >> 4;
    const int layer = (slot < 4) ? 0 : 1;
    const int s     = (slot < 4) ? slot : (slot - 4);
    const int kt    = s >> 1;
    const int ishi  = !(s & 1);

    short8 v;
    #pragma unroll
    for (int jj = 0; jj < 8; ++jj) {
        int k = kt * 32 + q4 * 8 + jj;
        float w = 0.f;
        if (n < NGATE) {
            if (layer == 0) {
                if (k < 50)       w = W_hh0[n * 50 + k];
                else if (k < 53)  w = W_ih0[n * 3 + (k - 50)];
                else if (k == 53) w = b_ih0[n] + b_hh0[n];
            } else {
                if (k < 50)        w = W_ih1[n * 50 + k];
                else if (k < 100)  w = W_hh1[n * 50 + (k - 50)];
                else if (k == 100) w = b_ih1[n] + b_hh1[n];
            }
        }
        unsigned short h = f2bf(w);
        v[jj] = (short)(ishi ? h : f2bf(w - bf2f(h)));
    }
    *(short8*)&ws[((size_t)fid * 64 + lane) * 8] = v;
}

// ---------------- main kernel: v7 wave-specialized pipeline @ 2 blocks/CU ----------------
// Round-9 insight (counters are per-CU): per-SIMD issue utilization is only ~18%
// -- the kernel is dependency-latency-bound with 2 waves/SIMD. This round: NB 8->4,
// grid 512 = 2 co-resident blocks/CU (launch_bounds 512,4 -> 128 VGPR cap). Unlike
// round 7's identical attempt (FETCH exploded re-gathering RAW weights under the
// cap), B-frags come from ws: any cap-forced remat is one coalesced dwordx4 from a
// 156-KB L2-resident buffer. Success gates: FETCH ~7MB, WRITE ~24KB.
__global__ __launch_bounds__(NTH, 4) void lstm_mfma_v8(
    const float* __restrict__ x,
    const unsigned short* __restrict__ ws,
    const float* __restrict__ fc_w, const float* __restrict__ fc_b,
    float* __restrict__ out)
{
    __shared__ unsigned short A0hi[16 * A0S], A0lo[16 * A0S];
    __shared__ unsigned short A1hi[16 * A1S], A1lo[16 * A1S];
    __shared__ float g0[208 * GS];     // layer0 gate preacts [n][batch]
    __shared__ float g1[208 * GS];     // layer1 gate preacts (one step behind)
    __shared__ float hBf[NB * 52];     // final-step hB (fp32) for the FC

    const int tid = threadIdx.x;
    const int n16 = tid & 15;
    const int q4  = (tid >> 4) & 3;
    const int wid = tid >> 6;
    const int lane = tid & 63;
    const int b0  = blockIdx.x * NB;

    // ---- zero A state ----
    for (int i = tid; i < 16 * A0S; i += NTH) { A0hi[i] = 0; A0lo[i] = 0; }
    for (int i = tid; i < 16 * A1S; i += NTH) { A1hi[i] = 0; A1lo[i] = 0; }
    __syncthreads();

    if (tid < NB) {
        A0hi[tid * A0S + 53]  = 0x3F80;   // bf16 1.0 (bias column)
        A1hi[tid * A1S + 100] = 0x3F80;
    }

    // ---- B-fragments from ws (coalesced; cheap to remat under the VGPR cap) ----
    const short8* wsf = (const short8*)ws;
    short8 f0h[5][2], f0l[5][2];       // layer0 waves: tiles wid + 3*i
    short8 f1h[3][4], f1l[3][4];       // layer1 waves: tiles (wid-3) + 5*i
    if (wid < 3) {
        #pragma unroll
        for (int i = 0; i < 5; ++i) {
            const int nt = wid + 3 * i;
            const bool nv = (nt < NTILES);
            const size_t gbase = (size_t)(nv ? nt : 0) * 12 * 64 + lane;
            #pragma unroll
            for (int kt = 0; kt < 2; ++kt) {
                f0h[i][kt] = nv ? wsf[gbase + (size_t)(kt * 2 + 0) * 64] : short8{};
                f0l[i][kt] = nv ? wsf[gbase + (size_t)(kt * 2 + 1) * 64] : short8{};
            }
        }
    } else {
        #pragma unroll
        for (int i = 0; i < 3; ++i) {
            const int nt = (wid - 3) + 5 * i;
            const bool nv = (nt < NTILES);
            const size_t gbase = (size_t)(nv ? nt : 0) * 12 * 64 + lane;
            #pragma unroll
            for (int kt = 0; kt < 4; ++kt) {
                f1h[i][kt] = nv ? wsf[gbase + (size_t)(4 + kt * 2 + 0) * 64] : short8{};
                f1l[i][kt] = nv ? wsf[gbase + (size_t)(4 + kt * 2 + 1) * 64] : short8{};
            }
        }
    }

    // ---- cell roles (NB=4: 100 threads per layer) ----
    const int cb0 = tid & 3,  up0 = tid >> 2;          // L0 cells: tid < 100
    const int t2  = tid - 256;
    const int cb1 = t2 & 3,   up1 = t2 >> 2;           // L1 cells: 256 <= tid < 356
    float c0a = 0.f, c0b = 0.f, cBa = 0.f, cBb = 0.f;

    // ---- x-writer role: threads 456..467 ----
    float xv = 0.f;
    size_t xbase = 0;
    int xb = 0, xc = 0;
    if (tid >= 456 && tid < 456 + NB * 3) {
        int i = tid - 456;
        xb = i / 3; xc = i - xb * 3;
        xbase = (size_t)(b0 + xb) * (TT * 3);
        float x0 = x[xbase + xc];                    // t = 0
        unsigned short h = f2bf(x0);
        A0hi[xb * A0S + 50 + xc] = h;
        A0lo[xb * A0S + 50 + xc] = f2bf(x0 - bf2f(h));
        xv = x[xbase + 3 + xc];                      // prefetch t = 1
    }
    __syncthreads();

    // ================= PIPELINED MAIN LOOP (TT+1 iterations) =================
    for (int t = 0; t <= TT; ++t) {
        // -------- phase M --------
        if (wid < 3) {
            if (t < TT) {
                short8 a0h_[2], a0l_[2];
                #pragma unroll
                for (int kt = 0; kt < 2; ++kt) {
                    a0h_[kt] = *(const short8*)&A0hi[n16 * A0S + kt * 32 + q4 * 8];
                    a0l_[kt] = *(const short8*)&A0lo[n16 * A0S + kt * 32 + q4 * 8];
                }
                #pragma unroll
                for (int i = 0; i < 5; ++i) {
                    const int nt = wid + 3 * i;
                    if (nt < NTILES) {
                        f32x4 aa = {0.f,0.f,0.f,0.f}, ab = {0.f,0.f,0.f,0.f};
                        aa = __builtin_amdgcn_mfma_f32_16x16x32_bf16(a0h_[0], f0h[i][0], aa, 0, 0, 0);
                        aa = __builtin_amdgcn_mfma_f32_16x16x32_bf16(a0l_[0], f0h[i][0], aa, 0, 0, 0);
                        aa = __builtin_amdgcn_mfma_f32_16x16x32_bf16(a0h_[0], f0l[i][0], aa, 0, 0, 0);
                        ab = __builtin_amdgcn_mfma_f32_16x16x32_bf16(a0h_[1], f0h[i][1], ab, 0, 0, 0);
                        ab = __builtin_amdgcn_mfma_f32_16x16x32_bf16(a0l_[1], f0h[i][1], ab, 0, 0, 0);
                        ab = __builtin_amdgcn_mfma_f32_16x16x32_bf16(a0h_[1], f0l[i][1], ab, 0, 0, 0);
                        if (q4 == 0)   // only batches 0..3 carry data
                            *(f32x4*)&g0[(nt * 16 + n16) * GS] = aa + ab;
                    }
                }
            }
        } else {
            if (t > 0) {
                short8 a1h_[4], a1l_[4];
                #pragma unroll
                for (int kt = 0; kt < 4; ++kt) {
                    a1h_[kt] = *(const short8*)&A1hi[n16 * A1S + kt * 32 + q4 * 8];
                    a1l_[kt] = *(const short8*)&A1lo[n16 * A1S + kt * 32 + q4 * 8];
                }
                #pragma unroll
                for (int i = 0; i < 3; ++i) {
                    const int nt = (wid - 3) + 5 * i;
                    if (nt < NTILES) {
                        f32x4 aa = {0.f,0.f,0.f,0.f}, ab = {0.f,0.f,0.f,0.f};
                        #pragma unroll
                        for (int kt = 0; kt < 2; ++kt) {
                            aa = __builtin_amdgcn_mfma_f32_16x16x32_bf16(a1h_[kt], f1h[i][kt], aa, 0, 0, 0);
                            aa = __builtin_amdgcn_mfma_f32_16x16x32_bf16(a1l_[kt], f1h[i][kt], aa, 0, 0, 0);
                            aa = __builtin_amdgcn_mfma_f32_16x16x32_bf16(a1h_[kt], f1l[i][kt], aa, 0, 0, 0);
                        }
                        #pragma unroll
                        for (int kt = 2; kt < 4; ++kt) {
                            ab = __builtin_amdgcn_mfma_f32_16x16x32_bf16(a1h_[kt], f1h[i][kt], ab, 0, 0, 0);
                            ab = __builtin_amdgcn_mfma_f32_16x16x32_bf16(a1l_[kt], f1h[i][kt], ab, 0, 0, 0);
                            ab = __builtin_amdgcn_mfma_f32_16x16x32_bf16(a1h_[kt], f1l[i][kt], ab, 0, 0, 0);
                        }
                        if (q4 == 0)
                            *(f32x4*)&g1[(nt * 16 + n16) * GS] = aa + ab;
                    }
                }
            }
        }
        __syncthreads();

        // -------- phase C --------
        if (tid < 100) {
            if (t < TT) {
                const int cu0 = 2 * up0, cu1 = cu0 + 1;
                float h0 = cell_h(g0[cu0 * GS + cb0],         g0[(cu0 + 50) * GS + cb0],
                                  g0[(cu0 + 100) * GS + cb0], g0[(cu0 + 150) * GS + cb0], c0a);
                float h1 = cell_h(g0[cu1 * GS + cb0],         g0[(cu1 + 50) * GS + cb0],
                                  g0[(cu1 + 100) * GS + cb0], g0[(cu1 + 150) * GS + cb0], c0b);
                unsigned short h0h = f2bf(h0), h1h = f2bf(h1);
                unsigned int vhi = (unsigned int)h0h | ((unsigned int)h1h << 16);
                unsigned int vlo = (unsigned int)f2bf(h0 - bf2f(h0h))
                                 | ((unsigned int)f2bf(h1 - bf2f(h1h)) << 16);
                *(unsigned int*)&A0hi[cb0 * A0S + cu0] = vhi;   // layer0 recurrent input
                *(unsigned int*)&A0lo[cb0 * A0S + cu0] = vlo;
                *(unsigned int*)&A1hi[cb0 * A1S + cu0] = vhi;   // layer1 input (consumed M(t+1))
                *(unsigned int*)&A1lo[cb0 * A1S + cu0] = vlo;
            }
        } else if (tid >= 256 && tid < 356) {
            if (t > 0) {
                const int cu0 = 2 * up1, cu1 = cu0 + 1;
                float h0 = cell_h(g1[cu0 * GS + cb1],         g1[(cu0 + 50) * GS + cb1],
                                  g1[(cu0 + 100) * GS + cb1], g1[(cu0 + 150) * GS + cb1], cBa);
                float h1 = cell_h(g1[cu1 * GS + cb1],         g1[(cu1 + 50) * GS + cb1],
                                  g1[(cu1 + 100) * GS + cb1], g1[(cu1 + 150) * GS + cb1], cBb);
                unsigned short h0h = f2bf(h0), h1h = f2bf(h1);
                unsigned int vhi = (unsigned int)h0h | ((unsigned int)h1h << 16);
                unsigned int vlo = (unsigned int)f2bf(h0 - bf2f(h0h))
                                 | ((unsigned int)f2bf(h1 - bf2f(h1h)) << 16);
                *(unsigned int*)&A1hi[cb1 * A1S + 50 + cu0] = vhi;  // recurrent hB
                *(unsigned int*)&A1lo[cb1 * A1S + 50 + cu0] = vlo;
                if (t == TT) {
                    hBf[cb1 * 52 + cu0] = h0;
                    hBf[cb1 * 52 + cu1] = h1;
                }
            }
        } else if (tid >= 456 && tid < 456 + NB * 3) {
            unsigned short h = f2bf(xv);                   // x(t+1) (clamped at tail; harmless)
            A0hi[xb * A0S + 50 + xc] = h;
            A0lo[xb * A0S + 50 + xc] = f2bf(xv - bf2f(h));
            int tn = (t + 2 < TT) ? (t + 2) : (TT - 1);
            xv = x[xbase + tn * 3 + xc];
        }
        __syncthreads();
    }

    // ======== final FC ========
    if (tid < NB * 3) {
        int bb = tid / 3, o = tid - bb * 3;
        float a = fc_b[o];
        #pragma unroll
        for (int uu = 0; uu < HH; ++uu)
            a += hBf[bb * 52 + uu] * fc_w[o * HH + uu];
        out[(size_t)(b0 + bb) * 3 + o] = a;
    }
}

extern "C" void kernel_launch(void* const* d_in, const int* in_sizes, int n_in,
                              void* d_out, int out_size, void* d_ws, size_t ws_size,
                              hipStream_t stream) {
    const float* x     = (const float*)d_in[0];
    const float* W_ih0 = (const float*)d_in[1];
    const float* W_hh0 = (const float*)d_in[2];
    const float* b_ih0 = (const float*)d_in[3];
    const float* b_hh0 = (const float*)d_in[4];
    const float* W_ih1 = (const float*)d_in[5];
    const float* W_hh1 = (const float*)d_in[6];
    const float* b_ih1 = (const float*)d_in[7];
    const float* b_hh1 = (const float*)d_in[8];
    const float* fc_w  = (const float*)d_in[9];
    const float* fc_b  = (const float*)d_in[10];
    float* out = (float*)d_out;
    unsigned short* ws = (unsigned short*)d_ws;   // needs NFRAG*64*16 B = 156 KB

    const int prepN = NFRAG * 64;
    prep_frags<<<(prepN + 255) / 256, 256, 0, stream>>>(
        W_ih0, W_hh0, b_ih0, b_hh0, W_ih1, W_hh1, b_ih1, b_hh1, ws);

    const int B = 2048;
    dim3 grid(B / NB), block(NTH);
    lstm_mfma_v8<<<grid, block, 0, stream>>>(x, ws, fc_w, fc_b, out);
}

// Round 11
// 1809.879 us; speedup vs baseline: 2.4521x; 2.4521x over previous
//
#include <hip/hip_runtime.h>

#define HH 50
#define NGATE 200      // 4*H gate rows
#define NB 8           // batch elements per block
#define TT 512
#define NTH 1024       // 16 waves -> 4 waves/SIMD at 1 block/CU
#define NTILES 13      // ceil(200/16)
#define A0S 72         // shorts/row: 64 k-slots (54 used: h|x|1) + 8 pad = 144B
#define A1S 136        // shorts/row: 128 k-slots (101 used: h1|hB|1) + 8 pad = 272B
#define GS 20          // g row stride (floats), rows indexed by gate n
#define NFRAG (NTILES * 12)   // 12 fragment slots per N-tile

typedef __attribute__((ext_vector_type(8))) short short8;
typedef __attribute__((ext_vector_type(4))) float f32x4;

__device__ __forceinline__ unsigned short f2bf(float f) {
    unsigned int u = __float_as_uint(f);
    u += 0x7FFFu + ((u >> 16) & 1u);
    return (unsigned short)(u >> 16);
}
__device__ __forceinline__ float bf2f(unsigned short s) {
    return __uint_as_float(((unsigned int)s) << 16);
}
__device__ __forceinline__ float fast_sigmoid(float v) {
    v = fminf(fmaxf(v, -30.f), 30.f);
    return 1.f / (1.f + __expf(-v));
}
__device__ __forceinline__ float fast_tanh(float v) {
    v = fminf(fmaxf(v, -15.f), 15.f);
    float e = __expf(2.f * v);
    return (e - 1.f) / (e + 1.f);
}
__device__ __forceinline__ float cell_h(float pi, float pf, float pg, float po, float& c) {
    float ii = fast_sigmoid(pi), ff = fast_sigmoid(pf);
    float gg = fast_tanh(pg),    oo = fast_sigmoid(po);
    c = ff * c + ii * gg;
    return oo * fast_tanh(c);
}

// ---------------- prep kernel: build split-bf16 B-fragments in d_ws ----------------
// slot map per N-tile nt:
//   slot 0..3  : layer0 kt{0,1} x {hi,lo}   (K = [Whh0(50)|Wih0(3)|bias1])
//   slot 4..11 : layer1 kt{0..3} x {hi,lo}  (K = [Wih1(50)|Whh1(50)|bias1])
__global__ void prep_frags(
    const float* __restrict__ W_ih0, const float* __restrict__ W_hh0,
    const float* __restrict__ b_ih0, const float* __restrict__ b_hh0,
    const float* __restrict__ W_ih1, const float* __restrict__ W_hh1,
    const float* __restrict__ b_ih1, const float* __restrict__ b_hh1,
    unsigned short* __restrict__ ws)
{
    int idx = blockIdx.x * blockDim.x + threadIdx.x;
    if (idx >= NFRAG * 64) return;
    const int lane = idx & 63;
    const int fid  = idx >> 6;
    const int nt   = fid / 12;
    const int slot = fid - nt * 12;
    const int n    = nt * 16 + (lane & 15);
    const int q4   = lane >> 4;
    const int layer = (slot < 4) ? 0 : 1;
    const int s     = (slot < 4) ? slot : (slot - 4);
    const int kt    = s >> 1;
    const int ishi  = !(s & 1);

    short8 v;
    #pragma unroll
    for (int jj = 0; jj < 8; ++jj) {
        int k = kt * 32 + q4 * 8 + jj;
        float w = 0.f;
        if (n < NGATE) {
            if (layer == 0) {
                if (k < 50)       w = W_hh0[n * 50 + k];
                else if (k < 53)  w = W_ih0[n * 3 + (k - 50)];
                else if (k == 53) w = b_ih0[n] + b_hh0[n];
            } else {
                if (k < 50)        w = W_ih1[n * 50 + k];
                else if (k < 100)  w = W_hh1[n * 50 + (k - 50)];
                else if (k == 100) w = b_ih1[n] + b_hh1[n];
            }
        }
        unsigned short h = f2bf(w);
        v[jj] = (short)(ishi ? h : f2bf(w - bf2f(h)));
    }
    *(short8*)&ws[((size_t)fid * 64 + lane) * 8] = v;
}

// ---------------- main kernel: 16-wave block, 4 waves/SIMD, frags resident ----------------
// Rounds 7/10 failed identically: with NTH=512 the compiler voluntarily shrank to
// 64 VGPRs (launch_bounds 2nd arg is a MIN) and demoted B-frags to per-step global
// reloads (round 10: FETCH 13.4 GB, 4438us). Fix: (a) one 1024-thread block/CU ->
// 4 waves/SIMD without needing 2 blocks; (b) amdgpu_waves_per_eu(4,4) pins the
// budget at exactly 128 VGPRs; (c) tiles spread over 16 waves so worst-case frag
// set is 64 VGPRs (L1: 2 tiles x 8 frags). Gates: VGPR=128, WRITE~24KB, FETCH~7MB.
__global__ __attribute__((amdgpu_flat_work_group_size(1024, 1024), amdgpu_waves_per_eu(4, 4)))
void lstm_mfma_v9(
    const float* __restrict__ x,
    const unsigned short* __restrict__ ws,
    const float* __restrict__ fc_w, const float* __restrict__ fc_b,
    float* __restrict__ out)
{
    __shared__ unsigned short A0hi[16 * A0S], A0lo[16 * A0S];
    __shared__ unsigned short A1hi[16 * A1S], A1lo[16 * A1S];
    __shared__ float g0[208 * GS];     // layer0 gate preacts [n][batch]
    __shared__ float g1[208 * GS];     // layer1 gate preacts (one step behind)
    __shared__ float hBf[NB * 52];     // final-step hB (fp32) for the FC

    const int tid = threadIdx.x;
    const int n16 = tid & 15;
    const int q4  = (tid >> 4) & 3;
    const int wid = tid >> 6;          // wave 0..15
    const int lane = tid & 63;
    const int b0  = blockIdx.x * NB;

    // ---- zero A state ----
    for (int i = tid; i < 16 * A0S; i += NTH) { A0hi[i] = 0; A0lo[i] = 0; }
    for (int i = tid; i < 16 * A1S; i += NTH) { A1hi[i] = 0; A1lo[i] = 0; }
    __syncthreads();

    if (tid < NB) {
        A0hi[tid * A0S + 53]  = 0x3F80;   // bf16 1.0 (bias column)
        A1hi[tid * A1S + 100] = 0x3F80;
    }

    // ---- B-fragments from ws ----
    // L0 MFMA waves 0..5:  tiles nt = wid + 6*i, i<3  (wave0: 3 tiles, others 2)
    // L1 MFMA waves 6..15: tiles nt = (wid-6) + 10*i, i<2 (waves 6-8: 2, 9-15: 1)
    const short8* wsf = (const short8*)ws;
    short8 f0h[3][2], f0l[3][2];
    short8 f1h[2][4], f1l[2][4];
    if (wid < 6) {
        #pragma unroll
        for (int i = 0; i < 3; ++i) {
            const int nt = wid + 6 * i;
            const bool nv = (nt < NTILES);
            const size_t gbase = (size_t)(nv ? nt : 0) * 12 * 64 + lane;
            #pragma unroll
            for (int kt = 0; kt < 2; ++kt) {
                f0h[i][kt] = nv ? wsf[gbase + (size_t)(kt * 2 + 0) * 64] : short8{};
                f0l[i][kt] = nv ? wsf[gbase + (size_t)(kt * 2 + 1) * 64] : short8{};
            }
        }
    } else {
        #pragma unroll
        for (int i = 0; i < 2; ++i) {
            const int nt = (wid - 6) + 10 * i;
            const bool nv = (nt < NTILES);
            const size_t gbase = (size_t)(nv ? nt : 0) * 12 * 64 + lane;
            #pragma unroll
            for (int kt = 0; kt < 4; ++kt) {
                f1h[i][kt] = nv ? wsf[gbase + (size_t)(4 + kt * 2 + 0) * 64] : short8{};
                f1l[i][kt] = nv ? wsf[gbase + (size_t)(4 + kt * 2 + 1) * 64] : short8{};
            }
        }
    }

    // ---- cell roles ----
    const int cb0 = tid & 7,  up0 = tid >> 3;          // L0 cells: tid < 200
    const int t2  = tid - 512;
    const int cb1 = t2 & 7,   up1 = t2 >> 3;           // L1 cells: 512 <= tid < 712
    float c0a = 0.f, c0b = 0.f, cBa = 0.f, cBb = 0.f;

    // ---- x-writer role: threads 960..983 (wave 15, light frag load) ----
    float xv = 0.f;
    size_t xbase = 0;
    int xb = 0, xc = 0;
    if (tid >= 960 && tid < 960 + NB * 3) {
        int i = tid - 960;
        xb = i / 3; xc = i - xb * 3;
        xbase = (size_t)(b0 + xb) * (TT * 3);
        float x0 = x[xbase + xc];                    // t = 0
        unsigned short h = f2bf(x0);
        A0hi[xb * A0S + 50 + xc] = h;
        A0lo[xb * A0S + 50 + xc] = f2bf(x0 - bf2f(h));
        xv = x[xbase + 3 + xc];                      // prefetch t = 1
    }
    __syncthreads();

    // ================= PIPELINED MAIN LOOP (TT+1 iterations) =================
    // iter t: phase M computes g0(t) [waves 0-5, t<TT] and g1(t-1) [waves 6-15, t>0];
    //         phase C computes h0(t) [t<TT] and hB(t-1) [t>0].
    for (int t = 0; t <= TT; ++t) {
        // -------- phase M --------
        if (wid < 6) {
            if (t < TT) {
                short8 a0h_[2], a0l_[2];
                #pragma unroll
                for (int kt = 0; kt < 2; ++kt) {
                    a0h_[kt] = *(const short8*)&A0hi[n16 * A0S + kt * 32 + q4 * 8];
                    a0l_[kt] = *(const short8*)&A0lo[n16 * A0S + kt * 32 + q4 * 8];
                }
                #pragma unroll
                for (int i = 0; i < 3; ++i) {
                    const int nt = wid + 6 * i;
                    if (nt < NTILES) {
                        f32x4 aa = {0.f,0.f,0.f,0.f}, ab = {0.f,0.f,0.f,0.f};
                        aa = __builtin_amdgcn_mfma_f32_16x16x32_bf16(a0h_[0], f0h[i][0], aa, 0, 0, 0);
                        aa = __builtin_amdgcn_mfma_f32_16x16x32_bf16(a0l_[0], f0h[i][0], aa, 0, 0, 0);
                        aa = __builtin_amdgcn_mfma_f32_16x16x32_bf16(a0h_[0], f0l[i][0], aa, 0, 0, 0);
                        ab = __builtin_amdgcn_mfma_f32_16x16x32_bf16(a0h_[1], f0h[i][1], ab, 0, 0, 0);
                        ab = __builtin_amdgcn_mfma_f32_16x16x32_bf16(a0l_[1], f0h[i][1], ab, 0, 0, 0);
                        ab = __builtin_amdgcn_mfma_f32_16x16x32_bf16(a0h_[1], f0l[i][1], ab, 0, 0, 0);
                        if (q4 < 2)   // batches 0..7
                            *(f32x4*)&g0[(nt * 16 + n16) * GS + q4 * 4] = aa + ab;
                    }
                }
            }
        } else {
            if (t > 0) {
                short8 a1h_[4], a1l_[4];
                #pragma unroll
                for (int kt = 0; kt < 4; ++kt) {
                    a1h_[kt] = *(const short8*)&A1hi[n16 * A1S + kt * 32 + q4 * 8];
                    a1l_[kt] = *(const short8*)&A1lo[n16 * A1S + kt * 32 + q4 * 8];
                }
                #pragma unroll
                for (int i = 0; i < 2; ++i) {
                    const int nt = (wid - 6) + 10 * i;
                    if (nt < NTILES) {
                        f32x4 aa = {0.f,0.f,0.f,0.f}, ab = {0.f,0.f,0.f,0.f};
                        #pragma unroll
                        for (int kt = 0; kt < 2; ++kt) {
                            aa = __builtin_amdgcn_mfma_f32_16x16x32_bf16(a1h_[kt], f1h[i][kt], aa, 0, 0, 0);
                            aa = __builtin_amdgcn_mfma_f32_16x16x32_bf16(a1l_[kt], f1h[i][kt], aa, 0, 0, 0);
                            aa = __builtin_amdgcn_mfma_f32_16x16x32_bf16(a1h_[kt], f1l[i][kt], aa, 0, 0, 0);
                        }
                        #pragma unroll
                        for (int kt = 2; kt < 4; ++kt) {
                            ab = __builtin_amdgcn_mfma_f32_16x16x32_bf16(a1h_[kt], f1h[i][kt], ab, 0, 0, 0);
                            ab = __builtin_amdgcn_mfma_f32_16x16x32_bf16(a1l_[kt], f1h[i][kt], ab, 0, 0, 0);
                            ab = __builtin_amdgcn_mfma_f32_16x16x32_bf16(a1h_[kt], f1l[i][kt], ab, 0, 0, 0);
                        }
                        if (q4 < 2)
                            *(f32x4*)&g1[(nt * 16 + n16) * GS + q4 * 4] = aa + ab;
                    }
                }
            }
        }
        __syncthreads();

        // -------- phase C --------
        if (tid < 200) {
            if (t < TT) {
                const int cu0 = 2 * up0, cu1 = cu0 + 1;
                float h0 = cell_h(g0[cu0 * GS + cb0],         g0[(cu0 + 50) * GS + cb0],
                                  g0[(cu0 + 100) * GS + cb0], g0[(cu0 + 150) * GS + cb0], c0a);
                float h1 = cell_h(g0[cu1 * GS + cb0],         g0[(cu1 + 50) * GS + cb0],
                                  g0[(cu1 + 100) * GS + cb0], g0[(cu1 + 150) * GS + cb0], c0b);
                unsigned short h0h = f2bf(h0), h1h = f2bf(h1);
                unsigned int vhi = (unsigned int)h0h | ((unsigned int)h1h << 16);
                unsigned int vlo = (unsigned int)f2bf(h0 - bf2f(h0h))
                                 | ((unsigned int)f2bf(h1 - bf2f(h1h)) << 16);
                *(unsigned int*)&A0hi[cb0 * A0S + cu0] = vhi;   // layer0 recurrent input
                *(unsigned int*)&A0lo[cb0 * A0S + cu0] = vlo;
                *(unsigned int*)&A1hi[cb0 * A1S + cu0] = vhi;   // layer1 input (consumed M(t+1))
                *(unsigned int*)&A1lo[cb0 * A1S + cu0] = vlo;
            }
        } else if (tid >= 512 && tid < 712) {
            if (t > 0) {
                const int cu0 = 2 * up1, cu1 = cu0 + 1;
                float h0 = cell_h(g1[cu0 * GS + cb1],         g1[(cu0 + 50) * GS + cb1],
                                  g1[(cu0 + 100) * GS + cb1], g1[(cu0 + 150) * GS + cb1], cBa);
                float h1 = cell_h(g1[cu1 * GS + cb1],         g1[(cu1 + 50) * GS + cb1],
                                  g1[(cu1 + 100) * GS + cb1], g1[(cu1 + 150) * GS + cb1], cBb);
                unsigned short h0h = f2bf(h0), h1h = f2bf(h1);
                unsigned int vhi = (unsigned int)h0h | ((unsigned int)h1h << 16);
                unsigned int vlo = (unsigned int)f2bf(h0 - bf2f(h0h))
                                 | ((unsigned int)f2bf(h1 - bf2f(h1h)) << 16);
                *(unsigned int*)&A1hi[cb1 * A1S + 50 + cu0] = vhi;  // recurrent hB
                *(unsigned int*)&A1lo[cb1 * A1S + 50 + cu0] = vlo;
                if (t == TT) {
                    hBf[cb1 * 52 + cu0] = h0;
                    hBf[cb1 * 52 + cu1] = h1;
                }
            }
        } else if (tid >= 960 && tid < 960 + NB * 3) {
            unsigned short h = f2bf(xv);                   // x(t+1) (clamped at tail; harmless)
            A0hi[xb * A0S + 50 + xc] = h;
            A0lo[xb * A0S + 50 + xc] = f2bf(xv - bf2f(h));
            int tn = (t + 2 < TT) ? (t + 2) : (TT - 1);
            xv = x[xbase + tn * 3 + xc];
        }
        __syncthreads();
    }

    // ======== final FC ========
    if (tid < NB * 3) {
        int bb = tid / 3, o = tid - bb * 3;
        float a = fc_b[o];
        #pragma unroll
        for (int uu = 0; uu < HH; ++uu)
            a += hBf[bb * 52 + uu] * fc_w[o * HH + uu];
        out[(size_t)(b0 + bb) * 3 + o] = a;
    }
}

extern "C" void kernel_launch(void* const* d_in, const int* in_sizes, int n_in,
                              void* d_out, int out_size, void* d_ws, size_t ws_size,
                              hipStream_t stream) {
    const float* x     = (const float*)d_in[0];
    const float* W_ih0 = (const float*)d_in[1];
    const float* W_hh0 = (const float*)d_in[2];
    const float* b_ih0 = (const float*)d_in[3];
    const float* b_hh0 = (const float*)d_in[4];
    const float* W_ih1 = (const float*)d_in[5];
    const float* W_hh1 = (const float*)d_in[6];
    const float* b_ih1 = (const float*)d_in[7];
    const float* b_hh1 = (const float*)d_in[8];
    const float* fc_w  = (const float*)d_in[9];
    const float* fc_b  = (const float*)d_in[10];
    float* out = (float*)d_out;
    unsigned short* ws = (unsigned short*)d_ws;   // needs NFRAG*64*16 B = 156 KB

    const int prepN = NFRAG * 64;
    prep_frags<<<(prepN + 255) / 256, 256, 0, stream>>>(
        W_ih0, W_hh0, b_ih0, b_hh0, W_ih1, W_hh1, b_ih1, b_hh1, ws);

    const int B = 2048;
    dim3 grid(B / NB), block(NTH);
    lstm_mfma_v9<<<grid, block, 0, stream>>>(x, ws, fc_w, fc_b, out);
}

// Round 12
// 1654.944 us; speedup vs baseline: 2.6816x; 1.0936x over previous
//
#include <hip/hip_runtime.h>

#define HH 50
#define NGATE 200      // 4*H gate rows
#define NB 4           // batch elements per block -> grid 512 = 2 blocks/CU resident
#define TT 512
#define NTH 512
#define NTILES 13      // ceil(200/16)
#define A0S 72         // shorts/row: 64 k-slots (54 used: h|x|1) + 8 pad = 144B
#define A1S 136        // shorts/row: 128 k-slots (101 used: h1|hB|1) + 8 pad = 272B
#define GS 20          // g row stride (floats), rows indexed by gate n
#define NFRAG (NTILES * 12)   // 12 fragment slots per N-tile

typedef __attribute__((ext_vector_type(8))) short short8;
typedef __attribute__((ext_vector_type(4))) float f32x4;

__device__ __forceinline__ unsigned short f2bf(float f) {
    unsigned int u = __float_as_uint(f);
    u += 0x7FFFu + ((u >> 16) & 1u);
    return (unsigned short)(u >> 16);
}
__device__ __forceinline__ float bf2f(unsigned short s) {
    return __uint_as_float(((unsigned int)s) << 16);
}
__device__ __forceinline__ float fast_sigmoid(float v) {
    v = fminf(fmaxf(v, -30.f), 30.f);
    return 1.f / (1.f + __expf(-v));
}
__device__ __forceinline__ float fast_tanh(float v) {
    v = fminf(fmaxf(v, -15.f), 15.f);
    float e = __expf(2.f * v);
    return (e - 1.f) / (e + 1.f);
}
__device__ __forceinline__ float cell_h(float pi, float pf, float pg, float po, float& c) {
    float ii = fast_sigmoid(pi), ff = fast_sigmoid(pf);
    float gg = fast_tanh(pg),    oo = fast_sigmoid(po);
    c = ff * c + ii * gg;
    return oo * fast_tanh(c);
}

// ---------------- prep kernel: build split-bf16 B-fragments in d_ws ----------------
// slot map per N-tile nt:
//   slot 0..3  : layer0 kt{0,1} x {hi,lo}   (K = [Whh0(50)|Wih0(3)|bias1])
//   slot 4..11 : layer1 kt{0..3} x {hi,lo}  (K = [Wih1(50)|Whh1(50)|bias1])
__global__ void prep_frags(
    const float* __restrict__ W_ih0, const float* __restrict__ W_hh0,
    const float* __restrict__ b_ih0, const float* __restrict__ b_hh0,
    const float* __restrict__ W_ih1, const float* __restrict__ W_hh1,
    const float* __restrict__ b_ih1, const float* __restrict__ b_hh1,
    unsigned short* __restrict__ ws)
{
    int idx = blockIdx.x * blockDim.x + threadIdx.x;
    if (idx >= NFRAG * 64) return;
    const int lane = idx & 63;
    const int fid  = idx >> 6;
    const int nt   = fid / 12;
    const int slot = fid - nt * 12;
    const int n    = nt * 16 + (lane & 15);
    const int q4   = lane >> 4;
    const int layer = (slot < 4) ? 0 : 1;
    const int s     = (slot < 4) ? slot : (slot - 4);
    const int kt    = s >> 1;
    const int ishi  = !(s & 1);

    short8 v;
    #pragma unroll
    for (int jj = 0; jj < 8; ++jj) {
        int k = kt * 32 + q4 * 8 + jj;
        float w = 0.f;
        if (n < NGATE) {
            if (layer == 0) {
                if (k < 50)       w = W_hh0[n * 50 + k];
                else if (k < 53)  w = W_ih0[n * 3 + (k - 50)];
                else if (k == 53) w = b_ih0[n] + b_hh0[n];
            } else {
                if (k < 50)        w = W_ih1[n * 50 + k];
                else if (k < 100)  w = W_hh1[n * 50 + (k - 50)];
                else if (k == 100) w = b_ih1[n] + b_hh1[n];
            }
        }
        unsigned short h = f2bf(w);
        v[jj] = (short)(ishi ? h : f2bf(w - bf2f(h)));
    }
    *(short8*)&ws[((size_t)fid * 64 + lane) * 8] = v;
}

// ---------------- main kernel: v7 pipeline, 2 HW-resident blocks/CU ----------------
// Occupancy saga: the allocator targets ~2x the requested min waves/EU
// (min=2 -> 128 VGPR [r9, no spill]; min=4 -> 64 VGPR [r10/r11, spills/demotion]).
// So: request min=2 (keeps the proven 128-VGPR binary) and let HARDWARE place two
// blocks/CU -- launch_bounds only constrains the compiler; residency is VGPR/LDS
// arithmetic: 4 waves/SIMD x 128 = 512 VGPRs ok, 2 x 47.5 KB LDS ok.
// NB=4, grid=512 supplies the second block that round 9 (grid=256) lacked.
// Gates: VGPR_Count == 128, WRITE ~24 KB, FETCH ~7-15 MB, Occupancy ~45%.
__global__ __launch_bounds__(NTH, 2) void lstm_mfma_v10(
    const float* __restrict__ x,
    const unsigned short* __restrict__ ws,
    const float* __restrict__ fc_w, const float* __restrict__ fc_b,
    float* __restrict__ out)
{
    __shared__ unsigned short A0hi[16 * A0S], A0lo[16 * A0S];
    __shared__ unsigned short A1hi[16 * A1S], A1lo[16 * A1S];
    __shared__ float g0[208 * GS];     // layer0 gate preacts [n][batch]
    __shared__ float g1[208 * GS];     // layer1 gate preacts (one step behind)
    __shared__ float hBf[NB * 52];     // final-step hB (fp32) for the FC

    const int tid = threadIdx.x;
    const int n16 = tid & 15;
    const int q4  = (tid >> 4) & 3;
    const int wid = tid >> 6;
    const int lane = tid & 63;
    const int b0  = blockIdx.x * NB;

    // ---- zero A state ----
    for (int i = tid; i < 16 * A0S; i += NTH) { A0hi[i] = 0; A0lo[i] = 0; }
    for (int i = tid; i < 16 * A1S; i += NTH) { A1hi[i] = 0; A1lo[i] = 0; }
    __syncthreads();

    if (tid < NB) {
        A0hi[tid * A0S + 53]  = 0x3F80;   // bf16 1.0 (bias column)
        A1hi[tid * A1S + 100] = 0x3F80;
    }

    // ---- B-fragments from ws (coalesced dwordx4 per frag) ----
    const short8* wsf = (const short8*)ws;
    short8 f0h[5][2], f0l[5][2];       // layer0 waves 0-2: tiles wid + 3*i
    short8 f1h[3][4], f1l[3][4];       // layer1 waves 3-7: tiles (wid-3) + 5*i
    if (wid < 3) {
        #pragma unroll
        for (int i = 0; i < 5; ++i) {
            const int nt = wid + 3 * i;
            const bool nv = (nt < NTILES);
            const size_t gbase = (size_t)(nv ? nt : 0) * 12 * 64 + lane;
            #pragma unroll
            for (int kt = 0; kt < 2; ++kt) {
                f0h[i][kt] = nv ? wsf[gbase + (size_t)(kt * 2 + 0) * 64] : short8{};
                f0l[i][kt] = nv ? wsf[gbase + (size_t)(kt * 2 + 1) * 64] : short8{};
            }
        }
    } else {
        #pragma unroll
        for (int i = 0; i < 3; ++i) {
            const int nt = (wid - 3) + 5 * i;
            const bool nv = (nt < NTILES);
            const size_t gbase = (size_t)(nv ? nt : 0) * 12 * 64 + lane;
            #pragma unroll
            for (int kt = 0; kt < 4; ++kt) {
                f1h[i][kt] = nv ? wsf[gbase + (size_t)(4 + kt * 2 + 0) * 64] : short8{};
                f1l[i][kt] = nv ? wsf[gbase + (size_t)(4 + kt * 2 + 1) * 64] : short8{};
            }
        }
    }

    // ---- cell roles (NB=4: 100 threads per layer) ----
    const int cb0 = tid & 3,  up0 = tid >> 2;          // L0 cells: tid < 100
    const int t2  = tid - 256;
    const int cb1 = t2 & 3,   up1 = t2 >> 2;           // L1 cells: 256 <= tid < 356
    float c0a = 0.f, c0b = 0.f, cBa = 0.f, cBb = 0.f;

    // ---- x-writer role: threads 456..467 ----
    float xv = 0.f;
    size_t xbase = 0;
    int xb = 0, xc = 0;
    if (tid >= 456 && tid < 456 + NB * 3) {
        int i = tid - 456;
        xb = i / 3; xc = i - xb * 3;
        xbase = (size_t)(b0 + xb) * (TT * 3);
        float x0 = x[xbase + xc];                    // t = 0
        unsigned short h = f2bf(x0);
        A0hi[xb * A0S + 50 + xc] = h;
        A0lo[xb * A0S + 50 + xc] = f2bf(x0 - bf2f(h));
        xv = x[xbase + 3 + xc];                      // prefetch t = 1
    }
    __syncthreads();

    // ================= PIPELINED MAIN LOOP (TT+1 iterations) =================
    for (int t = 0; t <= TT; ++t) {
        // -------- phase M --------
        if (wid < 3) {
            if (t < TT) {
                short8 a0h_[2], a0l_[2];
                #pragma unroll
                for (int kt = 0; kt < 2; ++kt) {
                    a0h_[kt] = *(const short8*)&A0hi[n16 * A0S + kt * 32 + q4 * 8];
                    a0l_[kt] = *(const short8*)&A0lo[n16 * A0S + kt * 32 + q4 * 8];
                }
                #pragma unroll
                for (int i = 0; i < 5; ++i) {
                    const int nt = wid + 3 * i;
                    if (nt < NTILES) {
                        f32x4 aa = {0.f,0.f,0.f,0.f}, ab = {0.f,0.f,0.f,0.f};
                        aa = __builtin_amdgcn_mfma_f32_16x16x32_bf16(a0h_[0], f0h[i][0], aa, 0, 0, 0);
                        aa = __builtin_amdgcn_mfma_f32_16x16x32_bf16(a0l_[0], f0h[i][0], aa, 0, 0, 0);
                        aa = __builtin_amdgcn_mfma_f32_16x16x32_bf16(a0h_[0], f0l[i][0], aa, 0, 0, 0);
                        ab = __builtin_amdgcn_mfma_f32_16x16x32_bf16(a0h_[1], f0h[i][1], ab, 0, 0, 0);
                        ab = __builtin_amdgcn_mfma_f32_16x16x32_bf16(a0l_[1], f0h[i][1], ab, 0, 0, 0);
                        ab = __builtin_amdgcn_mfma_f32_16x16x32_bf16(a0h_[1], f0l[i][1], ab, 0, 0, 0);
                        if (q4 == 0)   // only batches 0..3 carry data
                            *(f32x4*)&g0[(nt * 16 + n16) * GS] = aa + ab;
                    }
                }
            }
        } else {
            if (t > 0) {
                short8 a1h_[4], a1l_[4];
                #pragma unroll
                for (int kt = 0; kt < 4; ++kt) {
                    a1h_[kt] = *(const short8*)&A1hi[n16 * A1S + kt * 32 + q4 * 8];
                    a1l_[kt] = *(const short8*)&A1lo[n16 * A1S + kt * 32 + q4 * 8];
                }
                #pragma unroll
                for (int i = 0; i < 3; ++i) {
                    const int nt = (wid - 3) + 5 * i;
                    if (nt < NTILES) {
                        f32x4 aa = {0.f,0.f,0.f,0.f}, ab = {0.f,0.f,0.f,0.f};
                        #pragma unroll
                        for (int kt = 0; kt < 2; ++kt) {
                            aa = __builtin_amdgcn_mfma_f32_16x16x32_bf16(a1h_[kt], f1h[i][kt], aa, 0, 0, 0);
                            aa = __builtin_amdgcn_mfma_f32_16x16x32_bf16(a1l_[kt], f1h[i][kt], aa, 0, 0, 0);
                            aa = __builtin_amdgcn_mfma_f32_16x16x32_bf16(a1h_[kt], f1l[i][kt], aa, 0, 0, 0);
                        }
                        #pragma unroll
                        for (int kt = 2; kt < 4; ++kt) {
                            ab = __builtin_amdgcn_mfma_f32_16x16x32_bf16(a1h_[kt], f1h[i][kt], ab, 0, 0, 0);
                            ab = __builtin_amdgcn_mfma_f32_16x16x32_bf16(a1l_[kt], f1h[i][kt], ab, 0, 0, 0);
                            ab = __builtin_amdgcn_mfma_f32_16x16x32_bf16(a1h_[kt], f1l[i][kt], ab, 0, 0, 0);
                        }
                        if (q4 == 0)
                            *(f32x4*)&g1[(nt * 16 + n16) * GS] = aa + ab;
                    }
                }
            }
        }
        __syncthreads();

        // -------- phase C --------
        if (tid < 100) {
            if (t < TT) {
                const int cu0 = 2 * up0, cu1 = cu0 + 1;
                float h0 = cell_h(g0[cu0 * GS + cb0],         g0[(cu0 + 50) * GS + cb0],
                                  g0[(cu0 + 100) * GS + cb0], g0[(cu0 + 150) * GS + cb0], c0a);
                float h1 = cell_h(g0[cu1 * GS + cb0],         g0[(cu1 + 50) * GS + cb0],
                                  g0[(cu1 + 100) * GS + cb0], g0[(cu1 + 150) * GS + cb0], c0b);
                unsigned short h0h = f2bf(h0), h1h = f2bf(h1);
                unsigned int vhi = (unsigned int)h0h | ((unsigned int)h1h << 16);
                unsigned int vlo = (unsigned int)f2bf(h0 - bf2f(h0h))
                                 | ((unsigned int)f2bf(h1 - bf2f(h1h)) << 16);
                *(unsigned int*)&A0hi[cb0 * A0S + cu0] = vhi;   // layer0 recurrent input
                *(unsigned int*)&A0lo[cb0 * A0S + cu0] = vlo;
                *(unsigned int*)&A1hi[cb0 * A1S + cu0] = vhi;   // layer1 input (consumed M(t+1))
                *(unsigned int*)&A1lo[cb0 * A1S + cu0] = vlo;
            }
        } else if (tid >= 256 && tid < 356) {
            if (t > 0) {
                const int cu0 = 2 * up1, cu1 = cu0 + 1;
                float h0 = cell_h(g1[cu0 * GS + cb1],         g1[(cu0 + 50) * GS + cb1],
                                  g1[(cu0 + 100) * GS + cb1], g1[(cu0 + 150) * GS + cb1], cBa);
                float h1 = cell_h(g1[cu1 * GS + cb1],         g1[(cu1 + 50) * GS + cb1],
                                  g1[(cu1 + 100) * GS + cb1], g1[(cu1 + 150) * GS + cb1], cBb);
                unsigned short h0h = f2bf(h0), h1h = f2bf(h1);
                unsigned int vhi = (unsigned int)h0h | ((unsigned int)h1h << 16);
                unsigned int vlo = (unsigned int)f2bf(h0 - bf2f(h0h))
                                 | ((unsigned int)f2bf(h1 - bf2f(h1h)) << 16);
                *(unsigned int*)&A1hi[cb1 * A1S + 50 + cu0] = vhi;  // recurrent hB
                *(unsigned int*)&A1lo[cb1 * A1S + 50 + cu0] = vlo;
                if (t == TT) {
                    hBf[cb1 * 52 + cu0] = h0;
                    hBf[cb1 * 52 + cu1] = h1;
                }
            }
        } else if (tid >= 456 && tid < 456 + NB * 3) {
            unsigned short h = f2bf(xv);                   // x(t+1) (clamped at tail; harmless)
            A0hi[xb * A0S + 50 + xc] = h;
            A0lo[xb * A0S + 50 + xc] = f2bf(xv - bf2f(h));
            int tn = (t + 2 < TT) ? (t + 2) : (TT - 1);
            xv = x[xbase + tn * 3 + xc];
        }
        __syncthreads();
    }

    // ======== final FC ========
    if (tid < NB * 3) {
        int bb = tid / 3, o = tid - bb * 3;
        float a = fc_b[o];
        #pragma unroll
        for (int uu = 0; uu < HH; ++uu)
            a += hBf[bb * 52 + uu] * fc_w[o * HH + uu];
        out[(size_t)(b0 + bb) * 3 + o] = a;
    }
}

extern "C" void kernel_launch(void* const* d_in, const int* in_sizes, int n_in,
                              void* d_out, int out_size, void* d_ws, size_t ws_size,
                              hipStream_t stream) {
    const float* x     = (const float*)d_in[0];
    const float* W_ih0 = (const float*)d_in[1];
    const float* W_hh0 = (const float*)d_in[2];
    const float* b_ih0 = (const float*)d_in[3];
    const float* b_hh0 = (const float*)d_in[4];
    const float* W_ih1 = (const float*)d_in[5];
    const float* W_hh1 = (const float*)d_in[6];
    const float* b_ih1 = (const float*)d_in[7];
    const float* b_hh1 = (const float*)d_in[8];
    const float* fc_w  = (const float*)d_in[9];
    const float* fc_b  = (const float*)d_in[10];
    float* out = (float*)d_out;
    unsigned short* ws = (unsigned short*)d_ws;   // needs NFRAG*64*16 B = 156 KB

    const int prepN = NFRAG * 64;
    prep_frags<<<(prepN + 255) / 256, 256, 0, stream>>>(
        W_ih0, W_hh0, b_ih0, b_hh0, W_ih1, W_hh1, b_ih1, b_hh1, ws);

    const int B = 2048;
    dim3 grid(B / NB), block(NTH);
    lstm_mfma_v10<<<grid, block, 0, stream>>>(x, ws, fc_w, fc_b, out);
}